// Round 15
// baseline (115.806 us; speedup 1.0000x reference)
//
#include <hip/hip_runtime.h>
#include <hip/hip_bf16.h>
#include <math.h>

#define BB 8
#define NN 2048
#define INC 256
#define CC 128
#define NE 65536
#define CAP 128
#define MROWS (BB*NN)
#define BN_EPS 1e-5f
#define NT 9              // output col-tiles of 16 (8 -> hm, 1 -> s+pad)
#define NKC 8             // K chunks of 32 (K=256)
#define NFRAG (NT*NKC*64) // 4608 pre-packed fragments (72 KB)

typedef unsigned int uint32;
typedef unsigned long long u64;
typedef __attribute__((ext_vector_type(8))) short short8;
typedef __attribute__((ext_vector_type(4))) float f32x4;

__device__ inline ushort f2bf(float f) {
  __hip_bfloat16 b = __float2bfloat16(f);   // HW cvt, RNE
  return reinterpret_cast<ushort&>(b);
}
__device__ inline float bf2f(ushort h) {
  return __uint_as_float(((uint32)h) << 16);
}

__device__ inline void load_edge(const void* ei, int is64, int e, int& s, int& d) {
  if (is64) {
    const long long* p = (const long long*)ei;
    s = (int)p[e]; d = (int)p[NE + e];
  } else {
    const int* p = (const int*)ei;
    s = p[e]; d = p[NE + e];
  }
}

// ---- prep: one block per input row i; scatter-writes its 144 frag elements ----
__global__ __launch_bounds__(128) void k_prep(const float* __restrict__ W,
                                              const float* __restrict__ a,
                                              const int* __restrict__ ei32,
                                              uint4* __restrict__ pack,
                                              int* __restrict__ flag,
                                              int* __restrict__ row_cnt) {
  __shared__ float Wms[128];
  __shared__ float Was[8];
  __shared__ float red2[2][8];
  int i = blockIdx.x, tid = threadIdx.x;   // tid = channel c
  if (tid < 8) row_cnt[i * 8 + tid] = 0;
  if (i == 0 && tid == 0) {
    int nz = 0;
    for (int t = 1; t < 128; t += 2) nz |= (ei32[t] != 0);
    *flag = nz ? 0 : 1;      // 1 => int64 layout
  }
  const float* Wr = W + (size_t)i * 512;
  float w0 = Wr[tid], w1 = Wr[128 + tid], w2 = Wr[256 + tid], w3 = Wr[384 + tid];
  Wms[tid] = 0.25f * (w0 + w1 + w2 + w3);
  float asrc = a[tid], adst = a[128 + tid];
  float p[8] = {w0 * asrc, w1 * asrc, w2 * asrc, w3 * asrc,
                w0 * adst, w1 * adst, w2 * adst, w3 * adst};
  #pragma unroll
  for (int off = 32; off > 0; off >>= 1)
    #pragma unroll
    for (int j = 0; j < 8; ++j) p[j] += __shfl_xor(p[j], off, 64);
  int wv = tid >> 6, lane = tid & 63;
  if (lane == 0) {
    #pragma unroll
    for (int j = 0; j < 8; ++j) red2[wv][j] = p[j];
  }
  __syncthreads();
  if (tid < 8) Was[tid] = red2[0][tid] + red2[1][tid];
  __syncthreads();
  int kc = i >> 5, gq = (i >> 3) & 3, jj = i & 7;
  ushort* pu = (ushort*)pack;
  for (int w = tid; w < 144; w += 128) {
    int t = w >> 4, l16 = w & 15;
    int cch = t * 16 + l16;
    float v = (cch < CC) ? Wms[cch] : ((cch < CC + 8) ? Was[cch - CC] : 0.0f);
    int frag = (t * NKC + kc) * 64 + gq * 16 + l16;
    pu[(size_t)frag * 8 + jj] = f2bf(v);
  }
}

// ---- MFMA GEMM + edge-list build (R13 exact) ----
__global__ __launch_bounds__(512) void k_gemm(const float* __restrict__ x,
                                              const uint4* __restrict__ pack,
                                              const void* __restrict__ ei,
                                              const int* __restrict__ flag,
                                              ushort* __restrict__ hm,
                                              float* __restrict__ s,
                                              int* __restrict__ row_cnt,
                                              int* __restrict__ row_src) {
  __shared__ uint4 lp[NFRAG];   // 72 KB
  int tid = threadIdx.x;
  if (tid < 256) {
    int e = blockIdx.x * 256 + tid;
    int is64 = *flag;
    int src, dst;
    load_edge(ei, is64, e, src, dst);
    int pos = atomicAdd(&row_cnt[dst], 1);
    if (pos < CAP) row_src[dst * CAP + pos] = src;
  }
  #pragma unroll
  for (int i = 0; i < 9; ++i) lp[i * 512 + tid] = pack[i * 512 + tid];

  int lane = tid & 63, wv = tid >> 6;
  int rt = wv & 3, th = wv >> 2;
  int g = lane >> 4;
  int xrow = blockIdx.x * 64 + rt * 16 + (lane & 15);
  const float* xr = x + (size_t)xrow * INC;

  short8 xf[8];
  #pragma unroll
  for (int kc = 0; kc < 8; ++kc) {
    f32x4 xa = *(const f32x4*)(xr + kc * 32 + g * 8);
    f32x4 xb = *(const f32x4*)(xr + kc * 32 + g * 8 + 4);
    short8 t;
    t[0] = (short)f2bf(xa[0]); t[1] = (short)f2bf(xa[1]);
    t[2] = (short)f2bf(xa[2]); t[3] = (short)f2bf(xa[3]);
    t[4] = (short)f2bf(xb[0]); t[5] = (short)f2bf(xb[1]);
    t[6] = (short)f2bf(xb[2]); t[7] = (short)f2bf(xb[3]);
    xf[kc] = t;
  }
  __syncthreads();

  f32x4 acc[4];
  f32x4 accE = (f32x4)(0.0f);
  #pragma unroll
  for (int i = 0; i < 4; ++i) acc[i] = (f32x4)(0.0f);

  const short8* fr = (const short8*)lp;
  int tb = th * 4;
  #pragma unroll
  for (int kc = 0; kc < NKC; ++kc) {
    #pragma unroll
    for (int i = 0; i < 4; ++i) {
      short8 af = fr[((tb + i) * NKC + kc) * 64 + lane];
      acc[i] = __builtin_amdgcn_mfma_f32_16x16x32_bf16(af, xf[kc], acc[i], 0, 0, 0);
    }
    short8 ae = fr[(8 * NKC + kc) * 64 + lane];
    accE = __builtin_amdgcn_mfma_f32_16x16x32_bf16(ae, xf[kc], accE, 0, 0, 0);
  }

  ushort* hrow = hm + (size_t)xrow * CC;
  #pragma unroll
  for (int i = 0; i < 4; ++i) {
    int t = tb + i;
    uint32 p0 = (uint32)f2bf(acc[i][0]) | ((uint32)f2bf(acc[i][1]) << 16);
    uint32 p1 = (uint32)f2bf(acc[i][2]) | ((uint32)f2bf(acc[i][3]) << 16);
    *(uint2*)(hrow + t * 16 + g * 4) = make_uint2(p0, p1);
  }
  if (th == 1 && g < 2) {
    int b = xrow >> 11, n = xrow & (NN - 1);
    *(f32x4*)(s + ((size_t)n * BB + b) * 8 + g * 4) = accE;
  }
}

// ---- fused dedupe+sort+e+softmax+aggregate+BN-partials (R14 exact) ----
// IDEMPOTENT: reads row_cnt/row_src/s/hm, writes hout/part deterministically.
__global__ __launch_bounds__(256) void k_agg(const int* __restrict__ row_cnt,
                                             const int* __restrict__ row_src,
                                             const float* __restrict__ s,
                                             const uint2* __restrict__ hm2,
                                             uint2* __restrict__ hout2,
                                             f32x4* __restrict__ part) {
  __shared__ int rsrc[CAP], csrc[CAP];
  __shared__ float swgt[8][CAP];
  __shared__ float emat[8][CAP];
  __shared__ float sdl[8][4];
  __shared__ f32x4 redS[256];
  __shared__ f32x4 redQ[256];
  __shared__ uint32 bmask[64];     // 2048-bit node mask
  __shared__ int wcnt[2];
  int d = blockIdx.x, tid = threadIdx.x;
  int lane = tid & 63, wv = tid >> 6;
  int k0 = row_cnt[d]; if (k0 > CAP) k0 = CAP;

  if (tid < 64) bmask[tid] = 0u;
  if (tid < 32) {
    int b = tid >> 2, h = tid & 3;
    sdl[b][h] = s[((size_t)d * BB + b) * 8 + 4 + h];
  }
  if (tid < k0) rsrc[tid] = row_src[d * CAP + tid];
  __syncthreads();
  int keep = 0;
  if (tid < k0) {
    int sv = rsrc[tid];
    uint32 bit = 1u << (sv & 31);
    uint32 old = atomicOr(&bmask[sv >> 5], bit);
    keep = ((old & bit) == 0) ? 1 : 0;
  }
  u64 mask = __ballot(keep);
  int pos = __popcll(mask & ((1ull << lane) - 1ull));
  if (lane == 0 && wv < 2) wcnt[wv] = (int)__popcll(mask);
  __syncthreads();
  int base = (wv == 1) ? wcnt[0] : 0;
  if (keep) csrc[base + pos] = rsrc[tid];
  __syncthreads();
  int kd = wcnt[0] + wcnt[1];
  if (tid < kd) {
    int sv = csrc[tid], r = 0;
    for (int q = 0; q < kd; ++q) r += (csrc[q] < sv) ? 1 : 0;
    rsrc[r] = sv;
  }
  __syncthreads();

  {
    int jj = tid >> 3, bb = tid & 7;
    for (int j0 = 0; j0 < kd; j0 += 32) {
      int j = j0 + jj;
      if (j < kd) {
        int r = rsrc[j];
        f32x4 ss = *(const f32x4*)(s + ((size_t)r * BB + bb) * 8);
        float sum = 0.0f;
        #pragma unroll
        for (int h = 0; h < 4; ++h) {
          float v = ss[h] + sdl[bb][h];
          sum += (v > 0.0f) ? v : 0.2f * v;
        }
        emat[bb][j] = 0.25f * sum;
      }
    }
  }
  __syncthreads();

  int b0 = wv, b1 = wv + 4;
  float v00 = (lane < kd)      ? emat[b0][lane]      : -INFINITY;
  float v01 = (lane + 64 < kd) ? emat[b0][lane + 64] : -INFINITY;
  float v10 = (lane < kd)      ? emat[b1][lane]      : -INFINITY;
  float v11 = (lane + 64 < kd) ? emat[b1][lane + 64] : -INFINITY;
  float m0 = fmaxf(v00, v01), m1 = fmaxf(v10, v11);
  #pragma unroll
  for (int off = 32; off > 0; off >>= 1) {
    m0 = fmaxf(m0, __shfl_xor(m0, off, 64));
    m1 = fmaxf(m1, __shfl_xor(m1, off, 64));
  }
  float e00 = (lane < kd)      ? expf(v00 - m0) : 0.0f;
  float e01 = (lane + 64 < kd) ? expf(v01 - m0) : 0.0f;
  float e10 = (lane < kd)      ? expf(v10 - m1) : 0.0f;
  float e11 = (lane + 64 < kd) ? expf(v11 - m1) : 0.0f;
  float sum0 = e00 + e01, sum1 = e10 + e11;
  #pragma unroll
  for (int off = 32; off > 0; off >>= 1) {
    sum0 += __shfl_xor(sum0, off, 64);
    sum1 += __shfl_xor(sum1, off, 64);
  }
  float inv0 = (kd > 0) ? 1.0f / sum0 : 0.0f;
  float inv1 = (kd > 0) ? 1.0f / sum1 : 0.0f;
  swgt[b0][lane]      = e00 * inv0;
  swgt[b0][lane + 64] = e01 * inv0;
  swgt[b1][lane]      = e10 * inv1;
  swgt[b1][lane + 64] = e11 * inv1;

  int half = lane >> 5;
  int bsel = wv + half * 4;
  int cq = lane & 31;
  const uint2* hb = hm2 + (size_t)bsel * NN * 32;
  f32x4 a4 = (f32x4)(0.0f);
  #pragma unroll 4
  for (int j = 0; j < kd; ++j) {
    int r = rsrc[j];
    float w = swgt[bsel][j];
    uint2 u = hb[(size_t)r * 32 + cq];
    a4[0] += w * bf2f((ushort)(u.x & 0xffffu));
    a4[1] += w * bf2f((ushort)(u.x >> 16));
    a4[2] += w * bf2f((ushort)(u.y & 0xffffu));
    a4[3] += w * bf2f((ushort)(u.y >> 16));
  }
  uint2 o;
  o.x = (uint32)f2bf(a4[0]) | ((uint32)f2bf(a4[1]) << 16);
  o.y = (uint32)f2bf(a4[2]) | ((uint32)f2bf(a4[3]) << 16);
  hout2[((size_t)bsel * NN + d) * 32 + cq] = o;

  f32x4 rq;
  rq[0] = a4[0] * a4[0]; rq[1] = a4[1] * a4[1];
  rq[2] = a4[2] * a4[2]; rq[3] = a4[3] * a4[3];
  redS[tid] = a4; redQ[tid] = rq;
  __syncthreads();
  if (tid < 32) {
    f32x4 ts = (f32x4)(0.0f), tq = (f32x4)(0.0f);
    #pragma unroll
    for (int k = 0; k < 8; ++k) {
      int src = (k >> 1) * 64 + (k & 1) * 32 + tid;
      ts += redS[src]; tq += redQ[src];
    }
    f32x4 pa, pb;
    pa[0] = ts[0]; pa[1] = tq[0]; pa[2] = ts[1]; pa[3] = tq[1];
    pb[0] = ts[2]; pb[1] = tq[2]; pb[2] = ts[3]; pb[3] = tq[3];
    part[(size_t)d * 64 + 2 * tid]     = pa;
    part[(size_t)d * 64 + 2 * tid + 1] = pb;
  }
}

// ---- BN reduce (R14 exact) ----
__global__ __launch_bounds__(256) void k_bnred(const f32x4* __restrict__ part,
                                               const float* __restrict__ gamma,
                                               const float* __restrict__ beta,
                                               float* __restrict__ bntab) {
  __shared__ f32x4 red[256];
  int c = blockIdx.x, t = threadIdx.x;
  f32x4 acc = (f32x4)(0.0f);
  #pragma unroll
  for (int i = 0; i < 8; ++i)
    acc += part[(size_t)(t + 256 * i) * 64 + c];
  red[t] = acc;
  __syncthreads();
  for (int off = 128; off > 0; off >>= 1) {
    if (t < off) red[t] += red[t + off];
    __syncthreads();
  }
  if (t == 0) {
    f32x4 v = red[0];
    #pragma unroll
    for (int i = 0; i < 2; ++i) {
      int ch = 2 * c + i;
      float mean = v[2 * i] / (float)MROWS;
      float var  = v[2 * i + 1] / (float)MROWS - mean * mean;
      if (var < 0.0f) var = 0.0f;
      float scale = gamma[ch] / sqrtf(var + BN_EPS);
      bntab[ch] = scale;
      bntab[CC + ch] = beta[ch] - mean * scale;
    }
  }
}

// ---- normalize + ELU (R14 exact) ----
__global__ __launch_bounds__(256) void k_elu(const uint32* __restrict__ hout,
                                             const float* __restrict__ bntab,
                                             float* __restrict__ out) {
  __shared__ float bsc[CC], bsh[CC];
  int tid = threadIdx.x;
  if (tid < CC) {
    bsc[tid] = bntab[tid];
    bsh[tid] = bntab[CC + tid];
  }
  __syncthreads();
  int pbase = blockIdx.x * 1024 + tid;
  #pragma unroll
  for (int i = 0; i < 4; ++i) {
    int p = pbase + i * 256;
    int cp = p & 63;
    uint32 u = hout[p];
    float y0 = bf2f((ushort)(u & 0xffffu)) * bsc[2 * cp]     + bsh[2 * cp];
    float y1 = bf2f((ushort)(u >> 16))     * bsc[2 * cp + 1] + bsh[2 * cp + 1];
    float2 o;
    o.x = (y0 > 0.0f) ? y0 : expm1f(y0);
    o.y = (y1 > 0.0f) ? y1 : expm1f(y1);
    *(float2*)(out + 2 * (size_t)p) = o;
  }
}

extern "C" void kernel_launch(void* const* d_in, const int* in_sizes, int n_in,
                              void* d_out, int out_size, void* d_ws, size_t ws_size,
                              hipStream_t stream) {
  const float* x     = (const float*)d_in[0];
  const void*  ei    = d_in[1];
  const float* W     = (const float*)d_in[2];
  const float* a     = (const float*)d_in[3];
  const float* gamma = (const float*)d_in[4];
  const float* beta  = (const float*)d_in[5];
  float* out = (float*)d_out;

  char* p = (char*)d_ws;
  ushort* hm   = (ushort*)p; p += (size_t)MROWS * CC * 2;  // 4 MB (bf16, batch-major)
  uint32* hout = (uint32*)p; p += (size_t)MROWS * CC * 2;  // 4 MB (bf16 pairs)
  f32x4* part = (f32x4*)p; p += (size_t)NN * 64 * 16;      // 2 MB BN partials
  float* s    = (float*)p; p += (size_t)MROWS * 8 * 4;     // 512 KB (node-major)
  uint4* pack = (uint4*)p; p += (size_t)NFRAG * 16;        // 72 KB
  float* bntab = (float*)p; p += 4096;
  int* flag   = (int*)p;   p += 256;
  int* row_cnt  = (int*)p; p += NN * 4;
  int* row_src  = (int*)p; p += (size_t)NN * CAP * 4;      // 1 MB

  k_prep<<<INC, 128, 0, stream>>>(W, a, (const int*)ei, pack, flag, row_cnt);
  k_gemm<<<MROWS / 64, 512, 0, stream>>>(x, pack, ei, flag, hm, s, row_cnt, row_src);
  // ===== ATTRIBUTION ROUND: k_agg launched 5x (idempotent; output identical).
  // dur = T_fixed + 5*T_agg  =>  T_agg = (dur - 53.5us) / 4.
  for (int rep = 0; rep < 5; ++rep) {
    k_agg<<<NN, 256, 0, stream>>>(row_cnt, row_src, s, (const uint2*)hm,
                                  (uint2*)hout, part);
  }
  k_bnred<<<64, 256, 0, stream>>>(part, gamma, beta, bntab);
  k_elu<<<(MROWS * CC / 2) / 1024, 256, 0, stream>>>(hout, bntab, out);
}

// Round 16
// 56.454 us; speedup vs baseline: 2.0513x; 2.0513x over previous
//
#include <hip/hip_runtime.h>
#include <hip/hip_bf16.h>
#include <math.h>

#define BB 8
#define NN 2048
#define INC 256
#define CC 128
#define NE 65536
#define CAP 128
#define MROWS (BB*NN)
#define BN_EPS 1e-5f
#define NT 9              // output col-tiles of 16 (8 -> hm, 1 -> s+pad)
#define NKC 8             // K chunks of 32 (K=256)
#define NFRAG (NT*NKC*64) // 4608 pre-packed fragments (72 KB)

typedef unsigned int uint32;
typedef unsigned long long u64;
typedef __attribute__((ext_vector_type(8))) short short8;
typedef __attribute__((ext_vector_type(4))) float f32x4;

__device__ inline ushort f2bf(float f) {
  __hip_bfloat16 b = __float2bfloat16(f);   // HW cvt, RNE
  return reinterpret_cast<ushort&>(b);
}
__device__ inline float bf2f(ushort h) {
  return __uint_as_float(((uint32)h) << 16);
}

__device__ inline void load_edge(const void* ei, int is64, int e, int& s, int& d) {
  if (is64) {
    const long long* p = (const long long*)ei;
    s = (int)p[e]; d = (int)p[NE + e];
  } else {
    const int* p = (const int*)ei;
    s = p[e]; d = p[NE + e];
  }
}

// ---- prep: one block per input row i; scatter-writes its 144 frag elements ----
__global__ __launch_bounds__(128) void k_prep(const float* __restrict__ W,
                                              const float* __restrict__ a,
                                              const int* __restrict__ ei32,
                                              uint4* __restrict__ pack,
                                              int* __restrict__ flag,
                                              int* __restrict__ row_cnt) {
  __shared__ float Wms[128];
  __shared__ float Was[8];
  __shared__ float red2[2][8];
  int i = blockIdx.x, tid = threadIdx.x;   // tid = channel c
  if (tid < 8) row_cnt[i * 8 + tid] = 0;
  if (i == 0 && tid == 0) {
    int nz = 0;
    for (int t = 1; t < 128; t += 2) nz |= (ei32[t] != 0);
    *flag = nz ? 0 : 1;      // 1 => int64 layout
  }
  const float* Wr = W + (size_t)i * 512;
  float w0 = Wr[tid], w1 = Wr[128 + tid], w2 = Wr[256 + tid], w3 = Wr[384 + tid];
  Wms[tid] = 0.25f * (w0 + w1 + w2 + w3);
  float asrc = a[tid], adst = a[128 + tid];
  float p[8] = {w0 * asrc, w1 * asrc, w2 * asrc, w3 * asrc,
                w0 * adst, w1 * adst, w2 * adst, w3 * adst};
  #pragma unroll
  for (int off = 32; off > 0; off >>= 1)
    #pragma unroll
    for (int j = 0; j < 8; ++j) p[j] += __shfl_xor(p[j], off, 64);
  int wv = tid >> 6, lane = tid & 63;
  if (lane == 0) {
    #pragma unroll
    for (int j = 0; j < 8; ++j) red2[wv][j] = p[j];
  }
  __syncthreads();
  if (tid < 8) Was[tid] = red2[0][tid] + red2[1][tid];
  __syncthreads();
  int kc = i >> 5, gq = (i >> 3) & 3, jj = i & 7;
  ushort* pu = (ushort*)pack;
  for (int w = tid; w < 144; w += 128) {
    int t = w >> 4, l16 = w & 15;
    int cch = t * 16 + l16;
    float v = (cch < CC) ? Wms[cch] : ((cch < CC + 8) ? Was[cch - CC] : 0.0f);
    int frag = (t * NKC + kc) * 64 + gq * 16 + l16;
    pu[(size_t)frag * 8 + jj] = f2bf(v);
  }
}

// ---- MFMA GEMM + edge-list build: 512 blocks x 256 thr (32 rows, 4 waves) ----
// LDS 72 KB => exactly 2 blocks/CU: one block's MFMA overlaps the other's
// staging (R15 attribution: gemm had zero inter-block overlap at 1 block/CU).
__global__ __launch_bounds__(256) void k_gemm(const float* __restrict__ x,
                                              const uint4* __restrict__ pack,
                                              const void* __restrict__ ei,
                                              const int* __restrict__ flag,
                                              ushort* __restrict__ hm,
                                              float* __restrict__ s,
                                              int* __restrict__ row_cnt,
                                              int* __restrict__ row_src) {
  __shared__ uint4 lp[NFRAG];   // 72 KB
  int tid = threadIdx.x;
  if (tid < 128) {
    int e = blockIdx.x * 128 + tid;
    int is64 = *flag;
    int src, dst;
    load_edge(ei, is64, e, src, dst);
    int pos = atomicAdd(&row_cnt[dst], 1);
    if (pos < CAP) row_src[dst * CAP + pos] = src;
  }
  #pragma unroll
  for (int i = 0; i < 18; ++i) lp[i * 256 + tid] = pack[i * 256 + tid];

  int lane = tid & 63, wv = tid >> 6;
  int rt = wv & 1, th = wv >> 1;
  int g = lane >> 4;
  int xrow = blockIdx.x * 32 + rt * 16 + (lane & 15);
  const float* xr = x + (size_t)xrow * INC;

  short8 xf[8];
  #pragma unroll
  for (int kc = 0; kc < 8; ++kc) {
    f32x4 xa = *(const f32x4*)(xr + kc * 32 + g * 8);
    f32x4 xb = *(const f32x4*)(xr + kc * 32 + g * 8 + 4);
    short8 t;
    t[0] = (short)f2bf(xa[0]); t[1] = (short)f2bf(xa[1]);
    t[2] = (short)f2bf(xa[2]); t[3] = (short)f2bf(xa[3]);
    t[4] = (short)f2bf(xb[0]); t[5] = (short)f2bf(xb[1]);
    t[6] = (short)f2bf(xb[2]); t[7] = (short)f2bf(xb[3]);
    xf[kc] = t;
  }
  __syncthreads();

  f32x4 acc[4];
  f32x4 accE = (f32x4)(0.0f);
  #pragma unroll
  for (int i = 0; i < 4; ++i) acc[i] = (f32x4)(0.0f);

  const short8* fr = (const short8*)lp;
  int tb = th * 4;
  #pragma unroll
  for (int kc = 0; kc < NKC; ++kc) {
    #pragma unroll
    for (int i = 0; i < 4; ++i) {
      short8 af = fr[((tb + i) * NKC + kc) * 64 + lane];
      acc[i] = __builtin_amdgcn_mfma_f32_16x16x32_bf16(af, xf[kc], acc[i], 0, 0, 0);
    }
    if (th == 1) {
      short8 ae = fr[(8 * NKC + kc) * 64 + lane];
      accE = __builtin_amdgcn_mfma_f32_16x16x32_bf16(ae, xf[kc], accE, 0, 0, 0);
    }
  }

  ushort* hrow = hm + (size_t)xrow * CC;
  #pragma unroll
  for (int i = 0; i < 4; ++i) {
    int t = tb + i;
    uint32 p0 = (uint32)f2bf(acc[i][0]) | ((uint32)f2bf(acc[i][1]) << 16);
    uint32 p1 = (uint32)f2bf(acc[i][2]) | ((uint32)f2bf(acc[i][3]) << 16);
    *(uint2*)(hrow + t * 16 + g * 4) = make_uint2(p0, p1);
  }
  if (th == 1 && g < 2) {
    int b = xrow >> 11, n = xrow & (NN - 1);
    *(f32x4*)(s + ((size_t)n * BB + b) * 8 + g * 4) = accE;
  }
}

// ---- fused dedupe+sort+e+softmax+aggregate+BN-partials: one block per dst row ----
// Merged dedupe+rank (one scan over kept flags, saves a barrier + compact pass);
// gather unroll 8 for more outstanding loads.
__global__ __launch_bounds__(256) void k_agg(const int* __restrict__ row_cnt,
                                             const int* __restrict__ row_src,
                                             const float* __restrict__ s,
                                             const uint2* __restrict__ hm2,
                                             uint2* __restrict__ hout2,
                                             f32x4* __restrict__ part) {
  __shared__ int rsrc[CAP], srt[CAP], kf[CAP];
  __shared__ float swgt[8][CAP];
  __shared__ float emat[8][CAP];
  __shared__ float sdl[8][4];
  __shared__ f32x4 redS[256];
  __shared__ f32x4 redQ[256];
  __shared__ uint32 bmask[64];     // 2048-bit node mask
  __shared__ int wcnt[2];
  int d = blockIdx.x, tid = threadIdx.x;
  int lane = tid & 63, wv = tid >> 6;
  int k0 = row_cnt[d]; if (k0 > CAP) k0 = CAP;

  if (tid < 64) bmask[tid] = 0u;
  if (tid < 32) {
    int b = tid >> 2, h = tid & 3;
    sdl[b][h] = s[((size_t)d * BB + b) * 8 + 4 + h];
  }
  if (tid < k0) rsrc[tid] = row_src[d * CAP + tid];
  __syncthreads();
  // dedupe by src via bitmask; record keep flags
  int keep = 0;
  if (tid < k0) {
    int sv = rsrc[tid];
    uint32 bit = 1u << (sv & 31);
    uint32 old = atomicOr(&bmask[sv >> 5], bit);
    keep = ((old & bit) == 0) ? 1 : 0;
    kf[tid] = keep;
  }
  u64 mask = __ballot(keep);
  if (lane == 0 && wv < 2) wcnt[wv] = (int)__popcll(mask);
  __syncthreads();
  int kd = wcnt[0] + wcnt[1];
  // rank directly among kept entries (unique values) -> sorted unique list
  if (keep) {
    int sv = rsrc[tid], r = 0;
    for (int q = 0; q < k0; ++q) r += (kf[q] && rsrc[q] < sv) ? 1 : 0;
    srt[r] = sv;
  }
  __syncthreads();

  // ---- e-matrix: thread (jj=tid>>3, b=tid&7); node-contiguous s reads ----
  {
    int jj = tid >> 3, bb = tid & 7;
    for (int j0 = 0; j0 < kd; j0 += 32) {
      int j = j0 + jj;
      if (j < kd) {
        int r = srt[j];
        f32x4 ss = *(const f32x4*)(s + ((size_t)r * BB + bb) * 8);
        float sum = 0.0f;
        #pragma unroll
        for (int h = 0; h < 4; ++h) {
          float v = ss[h] + sdl[bb][h];
          sum += (v > 0.0f) ? v : 0.2f * v;
        }
        emat[bb][j] = 0.25f * sum;
      }
    }
  }
  __syncthreads();

  // ---- softmax: wave wv handles batches b0=wv, b1=wv+4 from LDS e-matrix ----
  int b0 = wv, b1 = wv + 4;
  float v00 = (lane < kd)      ? emat[b0][lane]      : -INFINITY;
  float v01 = (lane + 64 < kd) ? emat[b0][lane + 64] : -INFINITY;
  float v10 = (lane < kd)      ? emat[b1][lane]      : -INFINITY;
  float v11 = (lane + 64 < kd) ? emat[b1][lane + 64] : -INFINITY;
  float m0 = fmaxf(v00, v01), m1 = fmaxf(v10, v11);
  #pragma unroll
  for (int off = 32; off > 0; off >>= 1) {
    m0 = fmaxf(m0, __shfl_xor(m0, off, 64));
    m1 = fmaxf(m1, __shfl_xor(m1, off, 64));
  }
  float e00 = (lane < kd)      ? expf(v00 - m0) : 0.0f;
  float e01 = (lane + 64 < kd) ? expf(v01 - m0) : 0.0f;
  float e10 = (lane < kd)      ? expf(v10 - m1) : 0.0f;
  float e11 = (lane + 64 < kd) ? expf(v11 - m1) : 0.0f;
  float sum0 = e00 + e01, sum1 = e10 + e11;
  #pragma unroll
  for (int off = 32; off > 0; off >>= 1) {
    sum0 += __shfl_xor(sum0, off, 64);
    sum1 += __shfl_xor(sum1, off, 64);
  }
  float inv0 = (kd > 0) ? 1.0f / sum0 : 0.0f;
  float inv1 = (kd > 0) ? 1.0f / sum1 : 0.0f;
  swgt[b0][lane]      = e00 * inv0;
  swgt[b0][lane + 64] = e01 * inv0;
  swgt[b1][lane]      = e10 * inv1;
  swgt[b1][lane + 64] = e11 * inv1;
  // no sync: each wave reads only swgt rows it wrote

  // ---- gather: half-wave per batch; thread = (bsel, chquad) ----
  int half = lane >> 5;
  int bsel = wv + half * 4;            // = b0 or b1 (this wave's rows of swgt)
  int cq = lane & 31;                  // channels 4cq .. 4cq+3
  const uint2* hb = hm2 + (size_t)bsel * NN * 32;
  f32x4 a4 = (f32x4)(0.0f);
  #pragma unroll 8
  for (int j = 0; j < kd; ++j) {
    int r = srt[j];
    float w = swgt[bsel][j];
    uint2 u = hb[(size_t)r * 32 + cq];
    a4[0] += w * bf2f((ushort)(u.x & 0xffffu));
    a4[1] += w * bf2f((ushort)(u.x >> 16));
    a4[2] += w * bf2f((ushort)(u.y & 0xffffu));
    a4[3] += w * bf2f((ushort)(u.y >> 16));
  }
  uint2 o;
  o.x = (uint32)f2bf(a4[0]) | ((uint32)f2bf(a4[1]) << 16);
  o.y = (uint32)f2bf(a4[2]) | ((uint32)f2bf(a4[3]) << 16);
  hout2[((size_t)bsel * NN + d) * 32 + cq] = o;

  // ---- BN partials: fixed-order 8-batch tree, non-atomic store ----
  f32x4 rq;
  rq[0] = a4[0] * a4[0]; rq[1] = a4[1] * a4[1];
  rq[2] = a4[2] * a4[2]; rq[3] = a4[3] * a4[3];
  redS[tid] = a4; redQ[tid] = rq;
  __syncthreads();
  if (tid < 32) {
    f32x4 ts = (f32x4)(0.0f), tq = (f32x4)(0.0f);
    #pragma unroll
    for (int k = 0; k < 8; ++k) {
      int src = (k >> 1) * 64 + (k & 1) * 32 + tid;
      ts += redS[src]; tq += redQ[src];
    }
    f32x4 pa, pb;
    pa[0] = ts[0]; pa[1] = tq[0]; pa[2] = ts[1]; pa[3] = tq[1];
    pb[0] = ts[2]; pb[1] = tq[2]; pb[2] = ts[3]; pb[3] = tq[3];
    part[(size_t)d * 64 + 2 * tid]     = pa;
    part[(size_t)d * 64 + 2 * tid + 1] = pb;
  }
}

// ---- BN reduce: 64 blocks, one per channel-pair; deterministic tree ----
__global__ __launch_bounds__(256) void k_bnred(const f32x4* __restrict__ part,
                                               const float* __restrict__ gamma,
                                               const float* __restrict__ beta,
                                               float* __restrict__ bntab) {
  __shared__ f32x4 red[256];
  int c = blockIdx.x, t = threadIdx.x;
  f32x4 acc = (f32x4)(0.0f);
  #pragma unroll
  for (int i = 0; i < 8; ++i)
    acc += part[(size_t)(t + 256 * i) * 64 + c];
  red[t] = acc;
  __syncthreads();
  for (int off = 128; off > 0; off >>= 1) {
    if (t < off) red[t] += red[t + off];
    __syncthreads();
  }
  if (t == 0) {
    f32x4 v = red[0];
    #pragma unroll
    for (int i = 0; i < 2; ++i) {
      int ch = 2 * c + i;
      float mean = v[2 * i] / (float)MROWS;
      float var  = v[2 * i + 1] / (float)MROWS - mean * mean;
      if (var < 0.0f) var = 0.0f;
      float scale = gamma[ch] / sqrtf(var + BN_EPS);
      bntab[ch] = scale;
      bntab[CC + ch] = beta[ch] - mean * scale;
    }
  }
}

// ---- normalize + ELU (reads finished bn table) ----
__global__ __launch_bounds__(256) void k_elu(const uint32* __restrict__ hout,
                                             const float* __restrict__ bntab,
                                             float* __restrict__ out) {
  __shared__ float bsc[CC], bsh[CC];
  int tid = threadIdx.x;
  if (tid < CC) {
    bsc[tid] = bntab[tid];
    bsh[tid] = bntab[CC + tid];
  }
  __syncthreads();
  int pbase = blockIdx.x * 1024 + tid;
  #pragma unroll
  for (int i = 0; i < 4; ++i) {
    int p = pbase + i * 256;
    int cp = p & 63;
    uint32 u = hout[p];
    float y0 = bf2f((ushort)(u & 0xffffu)) * bsc[2 * cp]     + bsh[2 * cp];
    float y1 = bf2f((ushort)(u >> 16))     * bsc[2 * cp + 1] + bsh[2 * cp + 1];
    float2 o;
    o.x = (y0 > 0.0f) ? y0 : expm1f(y0);
    o.y = (y1 > 0.0f) ? y1 : expm1f(y1);
    *(float2*)(out + 2 * (size_t)p) = o;
  }
}

extern "C" void kernel_launch(void* const* d_in, const int* in_sizes, int n_in,
                              void* d_out, int out_size, void* d_ws, size_t ws_size,
                              hipStream_t stream) {
  const float* x     = (const float*)d_in[0];
  const void*  ei    = d_in[1];
  const float* W     = (const float*)d_in[2];
  const float* a     = (const float*)d_in[3];
  const float* gamma = (const float*)d_in[4];
  const float* beta  = (const float*)d_in[5];
  float* out = (float*)d_out;

  char* p = (char*)d_ws;
  ushort* hm   = (ushort*)p; p += (size_t)MROWS * CC * 2;  // 4 MB (bf16, batch-major)
  uint32* hout = (uint32*)p; p += (size_t)MROWS * CC * 2;  // 4 MB (bf16 pairs)
  f32x4* part = (f32x4*)p; p += (size_t)NN * 64 * 16;      // 2 MB BN partials
  float* s    = (float*)p; p += (size_t)MROWS * 8 * 4;     // 512 KB (node-major)
  uint4* pack = (uint4*)p; p += (size_t)NFRAG * 16;        // 72 KB
  float* bntab = (float*)p; p += 4096;
  int* flag   = (int*)p;   p += 256;
  int* row_cnt  = (int*)p; p += NN * 4;
  int* row_src  = (int*)p; p += (size_t)NN * CAP * 4;      // 1 MB

  k_prep<<<INC, 128, 0, stream>>>(W, a, (const int*)ei, pack, flag, row_cnt);
  k_gemm<<<512, 256, 0, stream>>>(x, pack, ei, flag, hm, s, row_cnt, row_src);
  k_agg<<<NN, 256, 0, stream>>>(row_cnt, row_src, s, (const uint2*)hm,
                                (uint2*)hout, part);
  k_bnred<<<64, 256, 0, stream>>>(part, gamma, beta, bntab);
  k_elu<<<(MROWS * CC / 2) / 1024, 256, 0, stream>>>(hout, bntab, out);
}

// Round 17
// 53.400 us; speedup vs baseline: 2.1686x; 1.0572x over previous
//
#include <hip/hip_runtime.h>
#include <hip/hip_bf16.h>
#include <math.h>

#define BB 8
#define NN 2048
#define INC 256
#define CC 128
#define NE 65536
#define CAP 128
#define MROWS (BB*NN)
#define BN_EPS 1e-5f
#define NT 9              // output col-tiles of 16 (8 -> hm, 1 -> s+pad)
#define NKC 8             // K chunks of 32 (K=256)
#define NFRAG (NT*NKC*64) // 4608 pre-packed fragments (72 KB)

typedef unsigned int uint32;
typedef unsigned long long u64;
typedef __attribute__((ext_vector_type(8))) short short8;
typedef __attribute__((ext_vector_type(4))) float f32x4;

__device__ inline ushort f2bf(float f) {
  __hip_bfloat16 b = __float2bfloat16(f);   // HW cvt, RNE
  return reinterpret_cast<ushort&>(b);
}
__device__ inline float bf2f(ushort h) {
  return __uint_as_float(((uint32)h) << 16);
}

__device__ inline void load_edge(const void* ei, int is64, int e, int& s, int& d) {
  if (is64) {
    const long long* p = (const long long*)ei;
    s = (int)p[e]; d = (int)p[NE + e];
  } else {
    const int* p = (const int*)ei;
    s = p[e]; d = p[NE + e];
  }
}

// ---- prep: one block per input row i; scatter-writes its 144 frag elements ----
// row i == fragment k-slot (kc=i>>5, g=(i>>3)&3, j=i&7).
__global__ __launch_bounds__(128) void k_prep(const float* __restrict__ W,
                                              const float* __restrict__ a,
                                              const int* __restrict__ ei32,
                                              uint4* __restrict__ pack,
                                              int* __restrict__ flag,
                                              int* __restrict__ row_cnt) {
  __shared__ float Wms[128];
  __shared__ float Was[8];
  __shared__ float red2[2][8];
  int i = blockIdx.x, tid = threadIdx.x;   // tid = channel c
  if (tid < 8) row_cnt[i * 8 + tid] = 0;
  if (i == 0 && tid == 0) {
    int nz = 0;
    for (int t = 1; t < 128; t += 2) nz |= (ei32[t] != 0);
    *flag = nz ? 0 : 1;      // 1 => int64 layout
  }
  const float* Wr = W + (size_t)i * 512;
  float w0 = Wr[tid], w1 = Wr[128 + tid], w2 = Wr[256 + tid], w3 = Wr[384 + tid];
  Wms[tid] = 0.25f * (w0 + w1 + w2 + w3);
  float asrc = a[tid], adst = a[128 + tid];
  float p[8] = {w0 * asrc, w1 * asrc, w2 * asrc, w3 * asrc,
                w0 * adst, w1 * adst, w2 * adst, w3 * adst};
  #pragma unroll
  for (int off = 32; off > 0; off >>= 1)
    #pragma unroll
    for (int j = 0; j < 8; ++j) p[j] += __shfl_xor(p[j], off, 64);
  int wv = tid >> 6, lane = tid & 63;
  if (lane == 0) {
    #pragma unroll
    for (int j = 0; j < 8; ++j) red2[wv][j] = p[j];
  }
  __syncthreads();
  if (tid < 8) Was[tid] = red2[0][tid] + red2[1][tid];
  __syncthreads();
  int kc = i >> 5, gq = (i >> 3) & 3, jj = i & 7;
  ushort* pu = (ushort*)pack;
  for (int w = tid; w < 144; w += 128) {
    int t = w >> 4, l16 = w & 15;
    int cch = t * 16 + l16;
    float v = (cch < CC) ? Wms[cch] : ((cch < CC + 8) ? Was[cch - CC] : 0.0f);
    int frag = (t * NKC + kc) * 64 + gq * 16 + l16;
    pu[(size_t)frag * 8 + jj] = f2bf(v);
  }
}

// ---- MFMA GEMM + edge-list build (R13/R14 exact) ----
// hm(bf16) batch-major [b][node][128]; s(f32) node-major [node][b][8].
__global__ __launch_bounds__(512) void k_gemm(const float* __restrict__ x,
                                              const uint4* __restrict__ pack,
                                              const void* __restrict__ ei,
                                              const int* __restrict__ flag,
                                              ushort* __restrict__ hm,
                                              float* __restrict__ s,
                                              int* __restrict__ row_cnt,
                                              int* __restrict__ row_src) {
  __shared__ uint4 lp[NFRAG];   // 72 KB
  int tid = threadIdx.x;
  if (tid < 256) {
    int e = blockIdx.x * 256 + tid;
    int is64 = *flag;
    int src, dst;
    load_edge(ei, is64, e, src, dst);
    int pos = atomicAdd(&row_cnt[dst], 1);
    if (pos < CAP) row_src[dst * CAP + pos] = src;
  }
  #pragma unroll
  for (int i = 0; i < 9; ++i) lp[i * 512 + tid] = pack[i * 512 + tid];

  int lane = tid & 63, wv = tid >> 6;
  int rt = wv & 3, th = wv >> 2;
  int g = lane >> 4;
  int xrow = blockIdx.x * 64 + rt * 16 + (lane & 15);
  const float* xr = x + (size_t)xrow * INC;

  short8 xf[8];
  #pragma unroll
  for (int kc = 0; kc < 8; ++kc) {
    f32x4 xa = *(const f32x4*)(xr + kc * 32 + g * 8);
    f32x4 xb = *(const f32x4*)(xr + kc * 32 + g * 8 + 4);
    short8 t;
    t[0] = (short)f2bf(xa[0]); t[1] = (short)f2bf(xa[1]);
    t[2] = (short)f2bf(xa[2]); t[3] = (short)f2bf(xa[3]);
    t[4] = (short)f2bf(xb[0]); t[5] = (short)f2bf(xb[1]);
    t[6] = (short)f2bf(xb[2]); t[7] = (short)f2bf(xb[3]);
    xf[kc] = t;
  }
  __syncthreads();

  f32x4 acc[4];
  f32x4 accE = (f32x4)(0.0f);
  #pragma unroll
  for (int i = 0; i < 4; ++i) acc[i] = (f32x4)(0.0f);

  const short8* fr = (const short8*)lp;
  int tb = th * 4;
  #pragma unroll
  for (int kc = 0; kc < NKC; ++kc) {
    #pragma unroll
    for (int i = 0; i < 4; ++i) {
      short8 af = fr[((tb + i) * NKC + kc) * 64 + lane];
      acc[i] = __builtin_amdgcn_mfma_f32_16x16x32_bf16(af, xf[kc], acc[i], 0, 0, 0);
    }
    short8 ae = fr[(8 * NKC + kc) * 64 + lane];
    accE = __builtin_amdgcn_mfma_f32_16x16x32_bf16(ae, xf[kc], accE, 0, 0, 0);
  }

  ushort* hrow = hm + (size_t)xrow * CC;
  #pragma unroll
  for (int i = 0; i < 4; ++i) {
    int t = tb + i;
    uint32 p0 = (uint32)f2bf(acc[i][0]) | ((uint32)f2bf(acc[i][1]) << 16);
    uint32 p1 = (uint32)f2bf(acc[i][2]) | ((uint32)f2bf(acc[i][3]) << 16);
    *(uint2*)(hrow + t * 16 + g * 4) = make_uint2(p0, p1);
  }
  if (th == 1 && g < 2) {
    int b = xrow >> 11, n = xrow & (NN - 1);
    *(f32x4*)(s + ((size_t)n * BB + b) * 8 + g * 4) = accE;
  }
}

// ---- fused dedupe+sort+e+softmax+aggregate+BN-partials (R14 exact) ----
__global__ __launch_bounds__(256) void k_agg(const int* __restrict__ row_cnt,
                                             const int* __restrict__ row_src,
                                             const float* __restrict__ s,
                                             const uint2* __restrict__ hm2,
                                             uint2* __restrict__ hout2,
                                             f32x4* __restrict__ part) {
  __shared__ int rsrc[CAP], csrc[CAP];
  __shared__ float swgt[8][CAP];
  __shared__ float emat[8][CAP];
  __shared__ float sdl[8][4];
  __shared__ f32x4 redS[256];
  __shared__ f32x4 redQ[256];
  __shared__ uint32 bmask[64];     // 2048-bit node mask
  __shared__ int wcnt[2];
  int d = blockIdx.x, tid = threadIdx.x;
  int lane = tid & 63, wv = tid >> 6;
  int k0 = row_cnt[d]; if (k0 > CAP) k0 = CAP;

  if (tid < 64) bmask[tid] = 0u;
  if (tid < 32) {
    int b = tid >> 2, h = tid & 3;
    sdl[b][h] = s[((size_t)d * BB + b) * 8 + 4 + h];
  }
  if (tid < k0) rsrc[tid] = row_src[d * CAP + tid];
  __syncthreads();
  // dedupe by src via bitmask
  int keep = 0;
  if (tid < k0) {
    int sv = rsrc[tid];
    uint32 bit = 1u << (sv & 31);
    uint32 old = atomicOr(&bmask[sv >> 5], bit);
    keep = ((old & bit) == 0) ? 1 : 0;
  }
  u64 mask = __ballot(keep);
  int pos = __popcll(mask & ((1ull << lane) - 1ull));
  if (lane == 0 && wv < 2) wcnt[wv] = (int)__popcll(mask);
  __syncthreads();
  int base = (wv == 1) ? wcnt[0] : 0;
  if (keep) csrc[base + pos] = rsrc[tid];
  __syncthreads();
  int kd = wcnt[0] + wcnt[1];
  // rank-sort by src value (unique) -> deterministic reduction order
  if (tid < kd) {
    int sv = csrc[tid], r = 0;
    for (int q = 0; q < kd; ++q) r += (csrc[q] < sv) ? 1 : 0;
    rsrc[r] = sv;
  }
  __syncthreads();

  // ---- e-matrix: thread (jj=tid>>3, b=tid&7); node-contiguous s reads ----
  {
    int jj = tid >> 3, bb = tid & 7;
    for (int j0 = 0; j0 < kd; j0 += 32) {
      int j = j0 + jj;
      if (j < kd) {
        int r = rsrc[j];
        f32x4 ss = *(const f32x4*)(s + ((size_t)r * BB + bb) * 8);
        float sum = 0.0f;
        #pragma unroll
        for (int h = 0; h < 4; ++h) {
          float v = ss[h] + sdl[bb][h];
          sum += (v > 0.0f) ? v : 0.2f * v;
        }
        emat[bb][j] = 0.25f * sum;
      }
    }
  }
  __syncthreads();

  // ---- softmax: wave wv handles batches b0=wv, b1=wv+4 from LDS e-matrix ----
  int b0 = wv, b1 = wv + 4;
  float v00 = (lane < kd)      ? emat[b0][lane]      : -INFINITY;
  float v01 = (lane + 64 < kd) ? emat[b0][lane + 64] : -INFINITY;
  float v10 = (lane < kd)      ? emat[b1][lane]      : -INFINITY;
  float v11 = (lane + 64 < kd) ? emat[b1][lane + 64] : -INFINITY;
  float m0 = fmaxf(v00, v01), m1 = fmaxf(v10, v11);
  #pragma unroll
  for (int off = 32; off > 0; off >>= 1) {
    m0 = fmaxf(m0, __shfl_xor(m0, off, 64));
    m1 = fmaxf(m1, __shfl_xor(m1, off, 64));
  }
  float e00 = (lane < kd)      ? expf(v00 - m0) : 0.0f;
  float e01 = (lane + 64 < kd) ? expf(v01 - m0) : 0.0f;
  float e10 = (lane < kd)      ? expf(v10 - m1) : 0.0f;
  float e11 = (lane + 64 < kd) ? expf(v11 - m1) : 0.0f;
  float sum0 = e00 + e01, sum1 = e10 + e11;
  #pragma unroll
  for (int off = 32; off > 0; off >>= 1) {
    sum0 += __shfl_xor(sum0, off, 64);
    sum1 += __shfl_xor(sum1, off, 64);
  }
  float inv0 = (kd > 0) ? 1.0f / sum0 : 0.0f;
  float inv1 = (kd > 0) ? 1.0f / sum1 : 0.0f;
  swgt[b0][lane]      = e00 * inv0;
  swgt[b0][lane + 64] = e01 * inv0;
  swgt[b1][lane]      = e10 * inv1;
  swgt[b1][lane + 64] = e11 * inv1;
  // no sync: each wave reads only swgt rows it wrote

  // ---- gather: half-wave per batch; thread = (bsel, chquad) ----
  int half = lane >> 5;
  int bsel = wv + half * 4;            // = b0 or b1 (this wave's rows of swgt)
  int cq = lane & 31;                  // channels 4cq .. 4cq+3
  const uint2* hb = hm2 + (size_t)bsel * NN * 32;
  f32x4 a4 = (f32x4)(0.0f);
  #pragma unroll 4
  for (int j = 0; j < kd; ++j) {
    int r = rsrc[j];
    float w = swgt[bsel][j];
    uint2 u = hb[(size_t)r * 32 + cq];
    a4[0] += w * bf2f((ushort)(u.x & 0xffffu));
    a4[1] += w * bf2f((ushort)(u.x >> 16));
    a4[2] += w * bf2f((ushort)(u.y & 0xffffu));
    a4[3] += w * bf2f((ushort)(u.y >> 16));
  }
  uint2 o;
  o.x = (uint32)f2bf(a4[0]) | ((uint32)f2bf(a4[1]) << 16);
  o.y = (uint32)f2bf(a4[2]) | ((uint32)f2bf(a4[3]) << 16);
  hout2[((size_t)bsel * NN + d) * 32 + cq] = o;

  // ---- BN partials: fixed-order 8-batch tree, non-atomic store ----
  f32x4 rq;
  rq[0] = a4[0] * a4[0]; rq[1] = a4[1] * a4[1];
  rq[2] = a4[2] * a4[2]; rq[3] = a4[3] * a4[3];
  redS[tid] = a4; redQ[tid] = rq;
  __syncthreads();
  if (tid < 32) {
    f32x4 ts = (f32x4)(0.0f), tq = (f32x4)(0.0f);
    #pragma unroll
    for (int k = 0; k < 8; ++k) {
      int src = (k >> 1) * 64 + (k & 1) * 32 + tid;
      ts += redS[src]; tq += redQ[src];
    }
    f32x4 pa, pb;
    pa[0] = ts[0]; pa[1] = tq[0]; pa[2] = ts[1]; pa[3] = tq[1];
    pb[0] = ts[2]; pb[1] = tq[2]; pb[2] = ts[3]; pb[3] = tq[3];
    part[(size_t)d * 64 + 2 * tid]     = pa;   // chpair 2*tid
    part[(size_t)d * 64 + 2 * tid + 1] = pb;   // chpair 2*tid+1
  }
}

// ---- BN reduce: 64 blocks, one per channel-pair; deterministic tree ----
__global__ __launch_bounds__(256) void k_bnred(const f32x4* __restrict__ part,
                                               const float* __restrict__ gamma,
                                               const float* __restrict__ beta,
                                               float* __restrict__ bntab) {
  __shared__ f32x4 red[256];
  int c = blockIdx.x, t = threadIdx.x;
  f32x4 acc = (f32x4)(0.0f);
  #pragma unroll
  for (int i = 0; i < 8; ++i)
    acc += part[(size_t)(t + 256 * i) * 64 + c];
  red[t] = acc;
  __syncthreads();
  for (int off = 128; off > 0; off >>= 1) {
    if (t < off) red[t] += red[t + off];
    __syncthreads();
  }
  if (t == 0) {
    f32x4 v = red[0];
    #pragma unroll
    for (int i = 0; i < 2; ++i) {
      int ch = 2 * c + i;
      float mean = v[2 * i] / (float)MROWS;
      float var  = v[2 * i + 1] / (float)MROWS - mean * mean;
      if (var < 0.0f) var = 0.0f;
      float scale = gamma[ch] / sqrtf(var + BN_EPS);
      bntab[ch] = scale;
      bntab[CC + ch] = beta[ch] - mean * scale;
    }
  }
}

// ---- normalize + ELU (reads finished bn table) ----
__global__ __launch_bounds__(256) void k_elu(const uint32* __restrict__ hout,
                                             const float* __restrict__ bntab,
                                             float* __restrict__ out) {
  __shared__ float bsc[CC], bsh[CC];
  int tid = threadIdx.x;
  if (tid < CC) {
    bsc[tid] = bntab[tid];
    bsh[tid] = bntab[CC + tid];
  }
  __syncthreads();
  int pbase = blockIdx.x * 1024 + tid;
  #pragma unroll
  for (int i = 0; i < 4; ++i) {
    int p = pbase + i * 256;      // pair index
    int cp = p & 63;
    uint32 u = hout[p];
    float y0 = bf2f((ushort)(u & 0xffffu)) * bsc[2 * cp]     + bsh[2 * cp];
    float y1 = bf2f((ushort)(u >> 16))     * bsc[2 * cp + 1] + bsh[2 * cp + 1];
    float2 o;
    o.x = (y0 > 0.0f) ? y0 : expm1f(y0);
    o.y = (y1 > 0.0f) ? y1 : expm1f(y1);
    *(float2*)(out + 2 * (size_t)p) = o;
  }
}

extern "C" void kernel_launch(void* const* d_in, const int* in_sizes, int n_in,
                              void* d_out, int out_size, void* d_ws, size_t ws_size,
                              hipStream_t stream) {
  const float* x     = (const float*)d_in[0];
  const void*  ei    = d_in[1];
  const float* W     = (const float*)d_in[2];
  const float* a     = (const float*)d_in[3];
  const float* gamma = (const float*)d_in[4];
  const float* beta  = (const float*)d_in[5];
  float* out = (float*)d_out;

  char* p = (char*)d_ws;
  ushort* hm   = (ushort*)p; p += (size_t)MROWS * CC * 2;  // 4 MB (bf16, batch-major)
  uint32* hout = (uint32*)p; p += (size_t)MROWS * CC * 2;  // 4 MB (bf16 pairs)
  f32x4* part = (f32x4*)p; p += (size_t)NN * 64 * 16;      // 2 MB BN partials
  float* s    = (float*)p; p += (size_t)MROWS * 8 * 4;     // 512 KB (node-major)
  uint4* pack = (uint4*)p; p += (size_t)NFRAG * 16;        // 72 KB
  float* bntab = (float*)p; p += 4096;
  int* flag   = (int*)p;   p += 256;
  int* row_cnt  = (int*)p; p += NN * 4;
  int* row_src  = (int*)p; p += (size_t)NN * CAP * 4;      // 1 MB

  k_prep<<<INC, 128, 0, stream>>>(W, a, (const int*)ei, pack, flag, row_cnt);
  k_gemm<<<MROWS / 64, 512, 0, stream>>>(x, pack, ei, flag, hm, s, row_cnt, row_src);
  k_agg<<<NN, 256, 0, stream>>>(row_cnt, row_src, s, (const uint2*)hm,
                                (uint2*)hout, part);
  k_bnred<<<64, 256, 0, stream>>>(part, gamma, beta, bntab);
  k_elu<<<(MROWS * CC / 2) / 1024, 256, 0, stream>>>(hout, bntab, out);
}